// Round 1
// 1098.058 us; speedup vs baseline: 1.1431x; 1.1431x over previous
//
#include <hip/hip_runtime.h>
#include <hip/hip_bf16.h>
#include <math.h>

// ExpertGroup: out = GELU_exact(x @ W1[e]^T) @ W2[e]^T
// x [16384, 2048], W1 [8, 4096, 2048], W2 [8, 2048, 4096], expert_idx scalar.
// Both GEMMs are A[M,K] x B[N,K]^T -> C[M,N].
//
// GEMM structure (this round): 256x256 tile, BK=32, 512 threads = 8 waves
// (2M x 4N), per-wave 128x64 output = acc[8][4] f32x4. LDS = ring of FOUR
// 32KB buffers (128KB), prefetch depth 3, counted s_waitcnt vmcnt(8) +
// raw s_barrier once per K-step (never __syncthreads in the loop -> no
// vmcnt(0) drain). LDS stored pair-interleaved 128B super-rows with
// chunk ^= (superrow&7) swizzle; global_load_lds stays linear and the
// SOURCE address is pre-swizzled (m173/m201 both-sides pattern) ->
// ds_read_b128 fragment reads are ~conflict-free. setprio(1) around the
// MFMA cluster; bijective XCD swizzle on the 1D grid.

typedef __bf16 bf16x8 __attribute__((ext_vector_type(8)));
typedef float floatx4 __attribute__((ext_vector_type(4)));

#define GLD16(gp, lp)                                                          \
  __builtin_amdgcn_global_load_lds(                                            \
      (__attribute__((address_space(1))) void*)(gp),                           \
      (__attribute__((address_space(3))) void*)(lp), 16, 0, 0)

__device__ __forceinline__ unsigned short f2bf(float f) {
  union { float f; unsigned int u; } v; v.f = f;
  unsigned int r = v.u + 0x7fffu + ((v.u >> 16) & 1u);   // RNE
  return (unsigned short)(r >> 16);
}

// Decide whether tensor inputs are bf16 (flag=1) or fp32 (flag=0).
__global__ void sniff_kernel(const unsigned short* __restrict__ x,
                             int* __restrict__ flag) {
  int lane = threadIdx.x & 63;
  unsigned short u = x[lane * 2];
  int e = (u >> 7) & 0xFF;
  bool ok = (e >= 118) && (e <= 133);
  unsigned long long m = __ballot(ok ? 1 : 0);
  if (lane == 0) flag[0] = (__popcll(m) > 32) ? 1 : 0;
}

// fp32 -> bf16 convert (no-op when inputs are already bf16).
__global__ void cvt_kernel(const float* __restrict__ in,
                           unsigned short* __restrict__ out,
                           const int* __restrict__ idxp, long long expert_stride,
                           const int* __restrict__ flagp) {
  if (flagp[0]) return;
  long long base = idxp ? (long long)idxp[0] * expert_stride : 0;
  long long i = ((long long)blockIdx.x * blockDim.x + threadIdx.x) * 4;
  float4 v = *(const float4*)(in + base + i);
  ushort4 o;
  o.x = f2bf(v.x); o.y = f2bf(v.y); o.z = f2bf(v.z); o.w = f2bf(v.w);
  *(ushort4*)(out + i) = o;
}

// C[M,N] = A[M,K] * B[N,K]^T, bf16 in, fp32 accum. M=16384 implicit.
template <bool GELU, int N, int K>
__global__ __launch_bounds__(512, 2) void gemm256(
    const unsigned short* __restrict__ Aws,   // pre-converted A (fp32 mode)
    const unsigned short* __restrict__ Araw,  // raw bf16 A (bf16 mode)
    const unsigned short* __restrict__ Bws,   // pre-converted expert slice
    const unsigned short* __restrict__ Braw,  // raw bf16 weights (all experts)
    const int* __restrict__ idxp, long long expert_stride,
    void* __restrict__ Cv, const int* __restrict__ flagp) {
  const int flag = flagp[0];
  const unsigned short* __restrict__ A = flag ? Araw : Aws;
  const unsigned short* __restrict__ B =
      flag ? (Braw + (long long)idxp[0] * expert_stride) : Bws;

  extern __shared__ __align__(16) char smem[];   // 4 slots x (A 16KB | B 16KB)

  constexpr int NT = K / 32;        // K-steps
  constexpr int NTN = N / 256;      // N tiles

  // Bijective XCD swizzle (nwg % 8 == 0 for both GEMMs).
  const int nwg = (int)gridDim.x;
  const int cpx = nwg >> 3;
  const int bid = (int)blockIdx.x;
  const int swz = (bid & 7) * cpx + (bid >> 3);
  const int m0 = (swz / NTN) * 256;
  const int n0 = (swz % NTN) * 256;

  const int tid  = (int)threadIdx.x;
  const int lane = tid & 63;
  const int wave = tid >> 6;
  const int lrow = lane & 15;
  const int quad = lane >> 4;
  const int wm = (wave >> 2) * 128;   // 0 / 128
  const int wn = (wave & 3) * 64;     // 0 / 64 / 128 / 192

  // ---- staging source coords (pre-swizzled global source, linear LDS dest).
  // LDS 16B slot u holds: s=u>>3 (128B super-row = global rows 2s,2s+1),
  // stored-chunk cw=u&7, logical chunk cp=cw^(s&7), row=2s+(cp>>2), kchunk=cp&3.
  auto decode = [](int u, int& r, int& c) {
    int s = u >> 3, cw = u & 7;
    int cp = cw ^ (s & 7);
    r = (s << 1) | (cp >> 2);
    c = cp & 3;
  };
  int ra0, ca0, ra1, ca1;
  decode(tid, ra0, ca0);
  decode(tid + 512, ra1, ca1);
  const unsigned short* gA0 = A + (long long)(m0 + ra0) * K + ca0 * 8;
  const unsigned short* gA1 = A + (long long)(m0 + ra1) * K + ca1 * 8;
  const unsigned short* gB0 = B + (long long)(n0 + ra0) * K + ca0 * 8;
  const unsigned short* gB1 = B + (long long)(n0 + ra1) * K + ca1 * 8;

  auto STAGE = [&](int t) {
    char* bb = smem + (t & 3) * 32768;
    GLD16(gA0 + t * 32, bb + tid * 16);
    GLD16(gA1 + t * 32, bb + 8192 + tid * 16);
    GLD16(gB0 + t * 32, bb + 16384 + tid * 16);
    GLD16(gB1 + t * 32, bb + 24576 + tid * 16);
  };

  // ---- fragment read offsets (apply the same swizzle on the read side).
  // row R = wm + i*16 + lrow, kchunk = quad:
  //   byte = (R>>1)*128 + ((((R&1)<<2)|quad) ^ ((R>>1)&7))*16
  //        = wm*64 + (lrow>>1)*128 + cpp*16 + i*1024   (cpp lane-constant)
  const int cpp = (quad | ((lrow & 1) << 2)) ^ ((lrow >> 1) & 7);
  const int aoff = wm * 64 + (lrow >> 1) * 128 + cpp * 16;
  const int boff = wn * 64 + (lrow >> 1) * 128 + cpp * 16;

  floatx4 acc[8][4] = {};

  // Prologue: prefetch tiles 0,1,2 (depth 3), wait tile 0 (vmcnt(8)).
  STAGE(0); STAGE(1); STAGE(2);
  asm volatile("s_waitcnt vmcnt(8)" ::: "memory");
  __builtin_amdgcn_s_barrier();
  asm volatile("" ::: "memory");

#pragma unroll 4
  for (int t = 0; t < NT; ++t) {
    char* bb = smem + (t & 3) * 32768;
    const char* Ab = bb + aoff;
    const char* Bb = bb + 16384 + boff;
    bf16x8 a[8], b[4];
#pragma unroll
    for (int j = 0; j < 4; ++j) b[j] = *(const bf16x8*)(Bb + j * 1024);
#pragma unroll
    for (int i = 0; i < 4; ++i) a[i] = *(const bf16x8*)(Ab + i * 1024);
    if (t + 3 < NT) STAGE(t + 3);   // writes slot (t-1)&3: readers done last block
#pragma unroll
    for (int i = 4; i < 8; ++i) a[i] = *(const bf16x8*)(Ab + i * 1024);
    __builtin_amdgcn_s_setprio(1);
#pragma unroll
    for (int i = 0; i < 8; ++i)
#pragma unroll
      for (int j = 0; j < 4; ++j)
        acc[i][j] = __builtin_amdgcn_mfma_f32_16x16x32_bf16(a[i], b[j],
                                                            acc[i][j], 0, 0, 0);
    __builtin_amdgcn_s_setprio(0);
    if (t + 1 < NT) {
      // Counted wait: tile t+1 must have landed; newest 8 loads (t+2,t+3)
      // stay in flight across the barrier (T4). Drains only at the tail.
      if (t + 3 < NT)      asm volatile("s_waitcnt vmcnt(8)" ::: "memory");
      else if (t + 2 < NT) asm volatile("s_waitcnt vmcnt(4)" ::: "memory");
      else                 asm volatile("s_waitcnt vmcnt(0)" ::: "memory");
      __builtin_amdgcn_s_barrier();
      asm volatile("" ::: "memory");
    }
  }

  // C/D layout (m89/m91-verified): col = lane&15, row = quad*4 + reg.
  if (GELU) {
    unsigned short* Cp = (unsigned short*)Cv;
#pragma unroll
    for (int i = 0; i < 8; ++i) {
      const int rb = m0 + wm + i * 16 + quad * 4;
#pragma unroll
      for (int j = 0; j < 4; ++j) {
        const int col = n0 + wn + j * 16 + lrow;
#pragma unroll
        for (int r = 0; r < 4; ++r) {
          float v = acc[i][j][r];
          v = 0.5f * v * (1.0f + erff(v * 0.70710678118654752f));
          Cp[(long long)(rb + r) * N + col] = f2bf(v);
        }
      }
    }
  } else if (flag) {  // bf16 output
    unsigned short* Cp = (unsigned short*)Cv;
#pragma unroll
    for (int i = 0; i < 8; ++i) {
      const int rb = m0 + wm + i * 16 + quad * 4;
#pragma unroll
      for (int j = 0; j < 4; ++j) {
        const int col = n0 + wn + j * 16 + lrow;
#pragma unroll
        for (int r = 0; r < 4; ++r)
          Cp[(long long)(rb + r) * N + col] = f2bf(acc[i][j][r]);
      }
    }
  } else {  // fp32 output
    float* Cp = (float*)Cv;
#pragma unroll
    for (int i = 0; i < 8; ++i) {
      const int rb = m0 + wm + i * 16 + quad * 4;
#pragma unroll
      for (int j = 0; j < 4; ++j) {
        const int col = n0 + wn + j * 16 + lrow;
#pragma unroll
        for (int r = 0; r < 4; ++r)
          Cp[(long long)(rb + r) * N + col] = acc[i][j][r];
      }
    }
  }
}

extern "C" void kernel_launch(void* const* d_in, const int* in_sizes, int n_in,
                              void* d_out, int out_size, void* d_ws,
                              size_t ws_size, hipStream_t stream) {
  const int* idxp = (const int*)d_in[0];
  const void* x  = d_in[1];   // [16384, 2048]
  const void* W1 = d_in[2];   // [8, 4096, 2048]
  const void* W2 = d_in[3];   // [8, 2048, 4096]

  // ws layout:
  //   [0,256)        : dtype flag
  //   [256, +128MiB) : h bf16 [16384, 4096]
  //   then x_bf16 (64 MiB), w1_bf16 (16 MiB), w2_bf16 (16 MiB)  (fp32 mode)
  char* ws = (char*)d_ws;
  int* flag = (int*)ws;
  unsigned short* h   = (unsigned short*)(ws + 256);
  unsigned short* xb  = (unsigned short*)(ws + 256 + 134217728LL);
  unsigned short* w1b = xb + 33554432LL;
  unsigned short* w2b = w1b + 8388608LL;

  // 128KB dynamic LDS opt-in (ignore errors; harmless if unnecessary).
  (void)hipFuncSetAttribute((const void*)gemm256<true, 4096, 2048>,
                            hipFuncAttributeMaxDynamicSharedMemorySize, 131072);
  (void)hipFuncSetAttribute((const void*)gemm256<false, 2048, 4096>,
                            hipFuncAttributeMaxDynamicSharedMemorySize, 131072);

  sniff_kernel<<<dim3(1), dim3(64), 0, stream>>>((const unsigned short*)x, flag);

  cvt_kernel<<<dim3(32768), dim3(256), 0, stream>>>((const float*)x, xb,
                                                    nullptr, 0, flag);
  cvt_kernel<<<dim3(8192), dim3(256), 0, stream>>>((const float*)W1, w1b,
                                                   idxp, 8388608LL, flag);
  cvt_kernel<<<dim3(8192), dim3(256), 0, stream>>>((const float*)W2, w2b,
                                                   idxp, 8388608LL, flag);

  // GEMM1: h = GELU(x @ W1[e]^T)   M=16384, N=4096, K=2048 -> 64x16 = 1024 wg
  gemm256<true, 4096, 2048><<<dim3(1024), dim3(512), 131072, stream>>>(
      xb, (const unsigned short*)x, w1b, (const unsigned short*)W1, idxp,
      8388608LL, h, flag);

  // GEMM2: out = h @ W2[e]^T       M=16384, N=2048, K=4096 -> 64x8 = 512 wg
  gemm256<false, 2048, 4096><<<dim3(512), dim3(512), 131072, stream>>>(
      h, h, w2b, (const unsigned short*)W2, idxp, 8388608LL, d_out, flag);
}

// Round 3
// 1049.526 us; speedup vs baseline: 1.1960x; 1.0462x over previous
//
#include <hip/hip_runtime.h>
#include <hip/hip_bf16.h>
#include <math.h>

// ExpertGroup: out = GELU_exact(x @ W1[e]^T) @ W2[e]^T
// x [16384, 2048], W1 [8, 4096, 2048], W2 [8, 2048, 4096], expert_idx scalar.
// Both GEMMs are A[M,K] x B[N,K]^T -> C[M,N].
//
// m201-style 8-phase GEMM: 256x256 tile, BK=64, 512 thr = 8 waves (2M x 4N),
// per-wave 128x64 = acc[8][4]. LDS = 2 dbuf x {A,B} x {k-half} x 16KB =
// 128 KB. Per K-tile: 4 phases over (kk, mh) quadrants: {ds_read_b128 subtile
// | stage 1 half-tile (2 gld_lds) | counted vmcnt gate at half boundaries |
// s_barrier | setprio(1) + 16 MFMA}. Gates: vmcnt(8) steady-state (never 0
// mid-loop), vmcnt(8)/(4)/(0) ladder at the tail — verified by in-order vmem
// retirement arithmetic. LDS halves use the round-1 pair-interleaved XOR
// swizzle (measured ZERO bank conflicts): 16B chunk of (row r, kchunk c)
// stored at super-row (r>>1), slot ((((r&1)<<2)|c) ^ ((r>>1)&7)); global
// SOURCE pre-swizzled, gld_lds dest linear (both-sides-or-neither rule).

typedef __bf16 bf16x8 __attribute__((ext_vector_type(8)));
typedef float floatx4 __attribute__((ext_vector_type(4)));

#define GLD16(gp, lp)                                                          \
  __builtin_amdgcn_global_load_lds(                                            \
      (__attribute__((address_space(1))) void*)(gp),                           \
      (__attribute__((address_space(3))) void*)(lp), 16, 0, 0)

#define WAITV8() asm volatile("s_waitcnt vmcnt(8)" ::: "memory")
#define WAITV4() asm volatile("s_waitcnt vmcnt(4)" ::: "memory")
#define WAITV0() asm volatile("s_waitcnt vmcnt(0)" ::: "memory")
#define BAR()    asm volatile("s_barrier" ::: "memory")

__device__ __forceinline__ unsigned short f2bf(float f) {
  union { float f; unsigned int u; } v; v.f = f;
  unsigned int r = v.u + 0x7fffu + ((v.u >> 16) & 1u);   // RNE
  return (unsigned short)(r >> 16);
}

// Decide whether tensor inputs are bf16 (flag=1) or fp32 (flag=0).
__global__ void sniff_kernel(const unsigned short* __restrict__ x,
                             int* __restrict__ flag) {
  int lane = threadIdx.x & 63;
  unsigned short u = x[lane * 2];
  int e = (u >> 7) & 0xFF;
  bool ok = (e >= 118) && (e <= 133);
  unsigned long long m = __ballot(ok ? 1 : 0);
  if (lane == 0) flag[0] = (__popcll(m) > 32) ? 1 : 0;
}

// fp32 -> bf16 convert (no-op when inputs are already bf16).
__global__ void cvt_kernel(const float* __restrict__ in,
                           unsigned short* __restrict__ out,
                           const int* __restrict__ idxp, long long expert_stride,
                           const int* __restrict__ flagp) {
  if (flagp[0]) return;
  long long base = idxp ? (long long)idxp[0] * expert_stride : 0;
  long long i = ((long long)blockIdx.x * blockDim.x + threadIdx.x) * 4;
  float4 v = *(const float4*)(in + base + i);
  ushort4 o;
  o.x = f2bf(v.x); o.y = f2bf(v.y); o.z = f2bf(v.z); o.w = f2bf(v.w);
  *(ushort4*)(out + i) = o;
}

// C[M,N] = A[M,K] * B[N,K]^T, bf16 in, fp32 accum. M=16384 implicit.
template <bool GELU, int N, int K>
__global__ __launch_bounds__(512, 2) void gemm256(
    const unsigned short* __restrict__ Aws,   // pre-converted A (fp32 mode)
    const unsigned short* __restrict__ Araw,  // raw bf16 A (bf16 mode)
    const unsigned short* __restrict__ Bws,   // pre-converted expert slice
    const unsigned short* __restrict__ Braw,  // raw bf16 weights (all experts)
    const int* __restrict__ idxp, long long expert_stride,
    void* __restrict__ Cv, const int* __restrict__ flagp) {
  const int flag = flagp[0];
  const unsigned short* __restrict__ A = flag ? Araw : Aws;
  const unsigned short* __restrict__ B =
      flag ? (Braw + (long long)idxp[0] * expert_stride) : Bws;

  extern __shared__ __align__(16) char smem[];
  // slot(d, tensor, kk) at offset d*65536 + tensor*32768 + kk*16384

  constexpr int NT2 = K / 64;       // K-tiles (BK=64)
  constexpr int NTN = N / 256;      // N tiles

  // Bijective XCD swizzle (nwg % 8 == 0 for both GEMMs).
  const int nwg = (int)gridDim.x;
  const int cpx = nwg >> 3;
  const int bid = (int)blockIdx.x;
  const int swz = (bid & 7) * cpx + (bid >> 3);
  const int m0 = (swz / NTN) * 256;
  const int n0 = (swz % NTN) * 256;

  const int tid  = (int)threadIdx.x;
  const int lane = tid & 63;
  const int wave = tid >> 6;
  const int lrow = lane & 15;
  const int quad = lane >> 4;
  const int wm = (wave >> 2) * 128;   // 0 / 128
  const int wn = (wave & 3) * 64;     // 0 / 64 / 128 / 192

  // ---- staging source coords (pre-swizzled global source, linear LDS dest).
  // Each 16KB half-buffer = 256 rows x 32 k-elems, 1024 16B chunks.
  // LDS chunk u: s=u>>3 (128B super-row = rows 2s,2s+1), stored slot cw=u&7,
  // logical cp=cw^(s&7), row=2s+(cp>>2), kchunk=cp&3.
  auto decode = [](int u, int& r, int& c) {
    int s = u >> 3, cw = u & 7;
    int cp = cw ^ (s & 7);
    r = (s << 1) | (cp >> 2);
    c = cp & 3;
  };
  int ra0, ca0, ra1, ca1;
  decode(tid, ra0, ca0);
  decode(tid + 512, ra1, ca1);
  const unsigned short* pA0 = A + (long long)(m0 + ra0) * K + ca0 * 8;
  const unsigned short* pA1 = A + (long long)(m0 + ra1) * K + ca1 * 8;
  const unsigned short* pB0 = B + (long long)(n0 + ra0) * K + ca0 * 8;
  const unsigned short* pB1 = B + (long long)(n0 + ra1) * K + ca1 * 8;

  // Stage half-tile (tensor, kk) of K-tile t: 2 gld_lds per thread.
  auto STAGE_A = [&](int t, int kk) {
    char* base = smem + (t & 1) * 65536 + kk * 16384;
    GLD16(pA0 + t * 64 + kk * 32, base + tid * 16);
    GLD16(pA1 + t * 64 + kk * 32, base + 8192 + tid * 16);
  };
  auto STAGE_B = [&](int t, int kk) {
    char* base = smem + (t & 1) * 65536 + 32768 + kk * 16384;
    GLD16(pB0 + t * 64 + kk * 32, base + tid * 16);
    GLD16(pB1 + t * 64 + kk * 32, base + 8192 + tid * 16);
  };

  // ---- fragment read offsets (same swizzle on the read side).
  // row R, kchunk=quad: byte = (R>>1)*128 + ((((R&1)<<2)|quad)^((R>>1)&7))*16
  // = wm*64 + (lrow>>1)*128 + cpp*16 + mfrag*1024  (cpp lane-constant).
  const int cpp = (quad | ((lrow & 1) << 2)) ^ ((lrow >> 1) & 7);
  const int aoff = wm * 64 + (lrow >> 1) * 128 + cpp * 16;
  const int boff = wn * 64 + (lrow >> 1) * 128 + cpp * 16;

  floatx4 acc[8][4] = {};

  // Prologue: stage tile0 (all 4 halves) + tile1 k0 halves, in the steady
  // stream order [Ak0,Bk0,Ak1,Bk1 | Ak0',Bk0']; gate oldest 2 halves.
  STAGE_A(0, 0); STAGE_B(0, 0); STAGE_A(0, 1); STAGE_B(0, 1);
  STAGE_A(1, 0); STAGE_B(1, 0);
  WAITV8();
  BAR();

#pragma unroll 2
  for (int T = 0; T < NT2; ++T) {
    const char* Ak0 = smem + (T & 1) * 65536 + aoff;
    const char* Bk0 = smem + (T & 1) * 65536 + 32768 + boff;
    bf16x8 a[4], b0[4], b1[4];

    // ---- P0: read A[mh0][kk0] + B[kk0]; stage A-k1(T+1); MFMA (kk0, mh0)
#pragma unroll
    for (int n = 0; n < 4; ++n) b0[n] = *(const bf16x8*)(Bk0 + n * 1024);
#pragma unroll
    for (int m = 0; m < 4; ++m) a[m] = *(const bf16x8*)(Ak0 + m * 1024);
    if (T + 1 < NT2) STAGE_A(T + 1, 1);
    BAR();
    __builtin_amdgcn_s_setprio(1);
#pragma unroll
    for (int m = 0; m < 4; ++m)
#pragma unroll
      for (int n = 0; n < 4; ++n)
        acc[m][n] = __builtin_amdgcn_mfma_f32_16x16x32_bf16(a[m], b0[n],
                                                            acc[m][n], 0, 0, 0);
    __builtin_amdgcn_s_setprio(0);

    // ---- P1: read A[mh1][kk0]; stage B-k1(T+1); gate; MFMA (kk0, mh1)
#pragma unroll
    for (int m = 0; m < 4; ++m)
      a[m] = *(const bf16x8*)(Ak0 + (4 + m) * 1024);
    if (T + 1 < NT2) STAGE_B(T + 1, 1);
    if (T < NT2 - 1) { WAITV8(); } else { WAITV0(); }
    BAR();
    __builtin_amdgcn_s_setprio(1);
#pragma unroll
    for (int m = 0; m < 4; ++m)
#pragma unroll
      for (int n = 0; n < 4; ++n)
        acc[4 + m][n] = __builtin_amdgcn_mfma_f32_16x16x32_bf16(
            a[m], b0[n], acc[4 + m][n], 0, 0, 0);
    __builtin_amdgcn_s_setprio(0);

    // ---- P2: read A[mh0][kk1] + B[kk1]; stage A-k0(T+2); MFMA (kk1, mh0)
#pragma unroll
    for (int n = 0; n < 4; ++n)
      b1[n] = *(const bf16x8*)(Bk0 + 16384 + n * 1024);
#pragma unroll
    for (int m = 0; m < 4; ++m)
      a[m] = *(const bf16x8*)(Ak0 + 16384 + m * 1024);
    if (T + 2 < NT2) STAGE_A(T + 2, 0);
    BAR();
    __builtin_amdgcn_s_setprio(1);
#pragma unroll
    for (int m = 0; m < 4; ++m)
#pragma unroll
      for (int n = 0; n < 4; ++n)
        acc[m][n] = __builtin_amdgcn_mfma_f32_16x16x32_bf16(a[m], b1[n],
                                                            acc[m][n], 0, 0, 0);
    __builtin_amdgcn_s_setprio(0);

    // ---- P3: read A[mh1][kk1]; stage B-k0(T+2); gate; MFMA (kk1, mh1)
#pragma unroll
    for (int m = 0; m < 4; ++m)
      a[m] = *(const bf16x8*)(Ak0 + 16384 + (4 + m) * 1024);
    if (T + 2 < NT2) STAGE_B(T + 2, 0);
    if (T < NT2 - 2) { WAITV8(); } else if (T == NT2 - 2) { WAITV4(); }
    BAR();
    __builtin_amdgcn_s_setprio(1);
#pragma unroll
    for (int m = 0; m < 4; ++m)
#pragma unroll
      for (int n = 0; n < 4; ++n)
        acc[4 + m][n] = __builtin_amdgcn_mfma_f32_16x16x32_bf16(
            a[m], b1[n], acc[4 + m][n], 0, 0, 0);
    __builtin_amdgcn_s_setprio(0);
  }

  // C/D layout (m89/m91-verified): col = lane&15, row = quad*4 + reg.
  if (GELU) {
    unsigned short* Cp = (unsigned short*)Cv;
#pragma unroll
    for (int i = 0; i < 8; ++i) {
      const int rb = m0 + wm + i * 16 + quad * 4;
#pragma unroll
      for (int j = 0; j < 4; ++j) {
        const int col = n0 + wn + j * 16 + lrow;
#pragma unroll
        for (int r = 0; r < 4; ++r) {
          float v = acc[i][j][r];
          v = 0.5f * v * (1.0f + erff(v * 0.70710678118654752f));
          Cp[(long long)(rb + r) * N + col] = f2bf(v);
        }
      }
    }
  } else if (flag) {  // bf16 output
    unsigned short* Cp = (unsigned short*)Cv;
#pragma unroll
    for (int i = 0; i < 8; ++i) {
      const int rb = m0 + wm + i * 16 + quad * 4;
#pragma unroll
      for (int j = 0; j < 4; ++j) {
        const int col = n0 + wn + j * 16 + lrow;
#pragma unroll
        for (int r = 0; r < 4; ++r)
          Cp[(long long)(rb + r) * N + col] = f2bf(acc[i][j][r]);
      }
    }
  } else {  // fp32 output
    float* Cp = (float*)Cv;
#pragma unroll
    for (int i = 0; i < 8; ++i) {
      const int rb = m0 + wm + i * 16 + quad * 4;
#pragma unroll
      for (int j = 0; j < 4; ++j) {
        const int col = n0 + wn + j * 16 + lrow;
#pragma unroll
        for (int r = 0; r < 4; ++r)
          Cp[(long long)(rb + r) * N + col] = acc[i][j][r];
      }
    }
  }
}

extern "C" void kernel_launch(void* const* d_in, const int* in_sizes, int n_in,
                              void* d_out, int out_size, void* d_ws,
                              size_t ws_size, hipStream_t stream) {
  const int* idxp = (const int*)d_in[0];
  const void* x  = d_in[1];   // [16384, 2048]
  const void* W1 = d_in[2];   // [8, 4096, 2048]
  const void* W2 = d_in[3];   // [8, 2048, 4096]

  // ws layout:
  //   [0,256)        : dtype flag
  //   [256, +128MiB) : h bf16 [16384, 4096]
  //   then x_bf16 (64 MiB), w1_bf16 (16 MiB), w2_bf16 (16 MiB)  (fp32 mode)
  char* ws = (char*)d_ws;
  int* flag = (int*)ws;
  unsigned short* h   = (unsigned short*)(ws + 256);
  unsigned short* xb  = (unsigned short*)(ws + 256 + 134217728LL);
  unsigned short* w1b = xb + 33554432LL;
  unsigned short* w2b = w1b + 8388608LL;

  (void)hipFuncSetAttribute((const void*)gemm256<true, 4096, 2048>,
                            hipFuncAttributeMaxDynamicSharedMemorySize, 131072);
  (void)hipFuncSetAttribute((const void*)gemm256<false, 2048, 4096>,
                            hipFuncAttributeMaxDynamicSharedMemorySize, 131072);

  sniff_kernel<<<dim3(1), dim3(64), 0, stream>>>((const unsigned short*)x, flag);

  cvt_kernel<<<dim3(32768), dim3(256), 0, stream>>>((const float*)x, xb,
                                                    nullptr, 0, flag);
  cvt_kernel<<<dim3(8192), dim3(256), 0, stream>>>((const float*)W1, w1b,
                                                   idxp, 8388608LL, flag);
  cvt_kernel<<<dim3(8192), dim3(256), 0, stream>>>((const float*)W2, w2b,
                                                   idxp, 8388608LL, flag);

  // GEMM1: h = GELU(x @ W1[e]^T)   M=16384, N=4096, K=2048 -> 64x16 = 1024 wg
  gemm256<true, 4096, 2048><<<dim3(1024), dim3(512), 131072, stream>>>(
      xb, (const unsigned short*)x, w1b, (const unsigned short*)W1, idxp,
      8388608LL, h, flag);

  // GEMM2: out = h @ W2[e]^T       M=16384, N=2048, K=4096 -> 64x8 = 512 wg
  gemm256<false, 2048, 4096><<<dim3(512), dim3(512), 131072, stream>>>(
      h, h, w2b, (const unsigned short*)W2, idxp, 8388608LL, d_out, flag);
}